// Round 3
// baseline (127.737 us; speedup 1.0000x reference)
//
#include <hip/hip_runtime.h>

#define VDIM   32
#define NPAIR  496              // 32*31/2
#define NBASIS 14               // DEG + ORDER - 1
#define NPARAM (NBASIS * NPAIR) // 6944
#define NINT   11               // distinct tap windows: i-3 in 0..10
#define ROWS   16               // rows per block
#define LROW   544              // padded lam row (floats): max seg(31)+31=542

typedef float f32x4 __attribute__((ext_vector_type(4)));

// Start of row v's segment in the quad-aligned lam layout:
// seg(v) = sum_{u=1}^{v-1} roundup4(u)  (each lm-row v has v lower-tri entries)
__device__ __forceinline__ int seg_of(int v) {
    int m = v - 1;
    if (m <= 0) return 0;
    int q = m >> 2, r = m & 3;
    return 4 * (2 * q * (q + 1) + r * (q + 1));
}

// ---- Pre-kernel: build ptv[p][i] = float4(params[i..i+3, p]) + penalties ----
__global__ __launch_bounds__(256) void Decorrelation_prep(
    const float* __restrict__ params,   // [14,496] k-major
    f32x4* __restrict__ ptv,            // [496][11] float4, 16B-aligned windows
    float* __restrict__ pens)           // [3]
{
    const int tid = threadIdx.x;
    for (int i = 0; i < NINT; ++i) {
        for (int p = tid; p < NPAIR; p += 256) {
            f32x4 w = { params[(i    ) * NPAIR + p],
                        params[(i + 1) * NPAIR + p],
                        params[(i + 2) * NPAIR + p],
                        params[(i + 3) * NPAIR + p] };
            ptv[p * NINT + i] = w;
        }
    }
    // penalties (reads are L1/L2 hits after the sweep above)
    float s2 = 0.f, s1 = 0.f, sp = 0.f;
    for (int idx = tid; idx < NPARAM; idx += 256) {
        const float a = params[idx];
        sp += a * a;
        if (idx < NPARAM - NPAIR) {
            const float b = params[idx + NPAIR];
            const float d1 = b - a;
            s1 += d1 * d1;
            if (idx < NPARAM - 2 * NPAIR) {
                const float c = params[idx + 2 * NPAIR];
                const float d2 = c - 2.f * b + a;
                s2 += d2 * d2;
            }
        }
    }
    #pragma unroll
    for (int off = 32; off > 0; off >>= 1) {
        s2 += __shfl_down(s2, off);
        s1 += __shfl_down(s1, off);
        sp += __shfl_down(sp, off);
    }
    __shared__ float ws[3][4];
    const int lane = tid & 63, wid = tid >> 6;
    if (lane == 0) { ws[0][wid] = s2; ws[1][wid] = s1; ws[2][wid] = sp; }
    __syncthreads();
    if (tid == 0) {
        pens[0] = ws[0][0] + ws[0][1] + ws[0][2] + ws[0][3];
        pens[1] = ws[1][0] + ws[1][1] + ws[1][2] + ws[1][3];
        pens[2] = ws[2][0] + ws[2][1] + ws[2][2] + ws[2][3];
    }
}

// ---- Main kernel: 1024 blocks x 256 threads, 16 rows/block ----
__global__ __launch_bounds__(256) void Decorrelation_35270271435435_kernel(
    const float* __restrict__ input,    // [N,32]
    const f32x4* __restrict__ ptv,      // [496][11] tap windows
    float* __restrict__ out,            // [N,32]
    float* __restrict__ lm,             // [N,32,32]
    int N)
{
    __shared__ f32x4 wgt4[ROWS][VDIM];  // 8 KB   basis weights per (r,c)
    __shared__ float xin [ROWS][VDIM];  // 2 KB   raw inputs
    __shared__ int   ibk [ROWS][VDIM];  // 2 KB   interval-3 (0..10)
    __shared__ float lam [ROWS][LROW];  // 34 KB  quad-aligned segmented lam

    const int tid = threadIdx.x;
    const int n0  = blockIdx.x * ROWS;

    // ---- Setup: 512 (r,c) items -> xin, weights, interval ----
    #pragma unroll
    for (int it = 0; it < 2; ++it) {
        const int item = tid + it * 256;
        const int r = item >> 5, c = item & 31;
        const int n = n0 + r;
        const float xi = (n < N) ? input[n * VDIM + c] : 0.0f;
        xin[r][c] = xi;
        const float dist = 30.0f / 11.0f;
        const float invd = 11.0f / 30.0f;
        const float t0   = -15.0f - 3.0f * dist;
        float x = fminf(fmaxf(xi, -15.0f), 15.0f - 1e-6f);
        float u = (x - t0) * invd;
        int   i = (int)floorf(u);
        i = min(13, max(3, i));
        const float uu  = u - (float)i;
        const float om  = 1.0f - uu;
        const float uu2 = uu * uu, uu3 = uu2 * uu;
        const float sixth = 1.0f / 6.0f;
        f32x4 w = { om * om * om * sixth,
                    (3.0f * uu3 - 6.0f * uu2 + 4.0f) * sixth,
                    (-3.0f * uu3 + 3.0f * uu2 + 3.0f * uu + 1.0f) * sixth,
                    uu3 * sixth };
        wgt4[r][c] = w;
        ibk[r][c]  = i - 3;
    }

    // ---- Per-thread pair decode (p1 = tid, p2 = tid+256), done once ----
    const int p1 = tid;
    int v1 = (int)((1.0f + sqrtf(8.0f * (float)p1 + 1.0f)) * 0.5f);
    while (v1 * (v1 - 1) / 2 > p1) --v1;
    while ((v1 + 1) * v1 / 2 <= p1) ++v1;
    const int c1 = p1 - v1 * (v1 - 1) / 2;
    const int o1 = seg_of(v1) + c1;

    const int  p2   = tid + 256;
    const bool has2 = (p2 < NPAIR);
    int v2 = 1, c2 = 0, o2 = 0;
    if (has2) {
        v2 = (int)((1.0f + sqrtf(8.0f * (float)p2 + 1.0f)) * 0.5f);
        while (v2 * (v2 - 1) / 2 > p2) --v2;
        while ((v2 + 1) * v2 / 2 <= p2) ++v2;
        c2 = p2 - v2 * (v2 - 1) / 2;
        o2 = seg_of(v2) + c2;
    }
    __syncthreads();

    // ---- Phase A: lam[r][seg(v)+c] for all pairs ----
    #pragma unroll 4
    for (int r = 0; r < ROWS; ++r) {
        {
            const f32x4 w = wgt4[r][c1];
            const f32x4 q = ptv[p1 * NINT + ibk[r][c1]];
            lam[r][o1] = w.x * q.x + w.y * q.y + w.z * q.z + w.w * q.w;
        }
        if (has2) {
            const f32x4 w = wgt4[r][c2];
            const f32x4 q = ptv[p2 * NINT + ibk[r][c2]];
            lam[r][o2] = w.x * q.x + w.y * q.y + w.z * q.z + w.w * q.w;
        }
    }
    __syncthreads();

    // ---- Phase B: emit lm (coalesced float4 NT stores) + out ----
    const int v    = tid >> 3;
    const int c0   = (tid & 7) << 2;
    const int segv = seg_of(v);
    float* lmp = lm + (size_t)n0 * (VDIM * VDIM) + tid * 4;

    #pragma unroll 4
    for (int r = 0; r < ROWS; ++r, lmp += VDIM * VDIM) {
        const int n = n0 + r;
        if (n >= N) break;
        const f32x4 lq = *(const f32x4*)&lam[r][segv + c0];
        const f32x4 xq = *(const f32x4*)&xin[r][c0];
        float vals[4];
        float partial = 0.0f;
        #pragma unroll
        for (int j = 0; j < 4; ++j) {
            const int c = c0 + j;
            const float lv = (j == 0) ? lq.x : (j == 1) ? lq.y : (j == 2) ? lq.z : lq.w;
            const float xv = (j == 0) ? xq.x : (j == 1) ? xq.y : (j == 2) ? xq.z : xq.w;
            const float val = (c < v) ? lv : ((c == v) ? 1.0f : 0.0f);
            vals[j] = val;
            partial += val * xv;
        }
        f32x4 f4 = { vals[0], vals[1], vals[2], vals[3] };
        __builtin_nontemporal_store(f4, (f32x4*)lmp);

        partial += __shfl_down(partial, 4, 8);
        partial += __shfl_down(partial, 2, 8);
        partial += __shfl_down(partial, 1, 8);
        if ((tid & 7) == 0) out[n * VDIM + v] = partial;
    }
}

extern "C" void kernel_launch(void* const* d_in, const int* in_sizes, int n_in,
                              void* d_out, int out_size, void* d_ws, size_t ws_size,
                              hipStream_t stream) {
    const float* input  = (const float*)d_in[0];   // [N,32]
    // d_in[1] = log_d : unused by the reference
    const float* params = (const float*)d_in[2];   // [14,496]
    const int N = in_sizes[0] / VDIM;              // 16384

    float* out  = (float*)d_out;                   // [N,32]
    float* lm   = out + (size_t)N * VDIM;          // [N,32,32]
    float* pens = lm + (size_t)N * VDIM * VDIM;    // [3]

    f32x4* ptv = (f32x4*)d_ws;                     // [496][11] float4 = 87 KB

    Decorrelation_prep<<<1, 256, 0, stream>>>(params, ptv, pens);

    const int nb = (N + ROWS - 1) / ROWS;          // 1024
    Decorrelation_35270271435435_kernel<<<nb, 256, 0, stream>>>(
        input, ptv, out, lm, N);
}

// Round 4
// 97.549 us; speedup vs baseline: 1.3095x; 1.3095x over previous
//
#include <hip/hip_runtime.h>

#define VDIM   32
#define NPAIR  496              // 32*31/2
#define NBASIS 14               // DEG + ORDER - 1
#define NPARAM (NBASIS * NPAIR) // 6944
#define NINT   11               // distinct tap windows: i-3 in 0..10
#define ROWS   8                // rows per block
#define LROW   544              // padded lam row (floats): max seg(31)+31=542

typedef float f32x4 __attribute__((ext_vector_type(4)));

// Start of row v's segment in the quad-aligned lam layout:
// seg(v) = sum_{u=1}^{v-1} roundup4(u)
__device__ __forceinline__ int seg_of(int v) {
    int m = v - 1;
    if (m <= 0) return 0;
    int q = m >> 2, r = m & 3;
    return 4 * (2 * q * (q + 1) + r * (q + 1));
}

// ---- Prep: ptv[i][p] = float4(params[i..i+3, p]); block 0 adds penalties ----
__global__ __launch_bounds__(256) void Decorrelation_prep(
    const float* __restrict__ params,   // [14,496] k-major
    f32x4* __restrict__ ptv,            // [11][496] float4 (i-major!)
    float* __restrict__ pens)           // [3]
{
    const int tid = threadIdx.x;
    const int i   = blockIdx.x;         // interval 0..10
    for (int p = tid; p < NPAIR; p += 256) {
        f32x4 w = { params[(i    ) * NPAIR + p],
                    params[(i + 1) * NPAIR + p],
                    params[(i + 2) * NPAIR + p],
                    params[(i + 3) * NPAIR + p] };
        ptv[i * NPAIR + p] = w;
    }
    if (blockIdx.x == 0) {
        float s2 = 0.f, s1 = 0.f, sp = 0.f;
        for (int idx = tid; idx < NPARAM; idx += 256) {
            const float a = params[idx];
            sp += a * a;
            if (idx < NPARAM - NPAIR) {
                const float b = params[idx + NPAIR];
                const float d1 = b - a;
                s1 += d1 * d1;
                if (idx < NPARAM - 2 * NPAIR) {
                    const float c = params[idx + 2 * NPAIR];
                    const float d2 = c - 2.f * b + a;
                    s2 += d2 * d2;
                }
            }
        }
        #pragma unroll
        for (int off = 32; off > 0; off >>= 1) {
            s2 += __shfl_down(s2, off);
            s1 += __shfl_down(s1, off);
            sp += __shfl_down(sp, off);
        }
        __shared__ float ws[3][4];
        const int lane = tid & 63, wid = tid >> 6;
        if (lane == 0) { ws[0][wid] = s2; ws[1][wid] = s1; ws[2][wid] = sp; }
        __syncthreads();
        if (tid == 0) {
            pens[0] = ws[0][0] + ws[0][1] + ws[0][2] + ws[0][3];
            pens[1] = ws[1][0] + ws[1][1] + ws[1][2] + ws[1][3];
            pens[2] = ws[2][0] + ws[2][1] + ws[2][2] + ws[2][3];
        }
    }
}

// ---- Main: 2048 blocks x 256 threads, 8 rows/block, ~22.3 KB LDS ----
__global__ __launch_bounds__(256) void Decorrelation_35270271435435_kernel(
    const float* __restrict__ input,    // [N,32]
    const f32x4* __restrict__ ptv,      // [11][496] tap windows, i-major
    float* __restrict__ out,            // [N,32]
    float* __restrict__ lm,             // [N,32,32]
    int N)
{
    __shared__ f32x4         wgt4[ROWS][VDIM];  // 4 KB
    __shared__ float         xin [ROWS][VDIM];  // 1 KB
    __shared__ unsigned char ibk [ROWS][VDIM];  // 256 B  (interval-3: 0..10)
    __shared__ float         lam [ROWS][LROW];  // 17.4 KB quad-aligned segments

    const int tid = threadIdx.x;
    const int n0  = blockIdx.x * ROWS;

    // ---- Setup: 256 (r,c) items, exactly 1 per thread ----
    {
        const int r = tid >> 5, c = tid & 31;
        const int n = n0 + r;
        const float xi = (n < N) ? input[n * VDIM + c] : 0.0f;
        xin[r][c] = xi;
        const float dist = 30.0f / 11.0f;
        const float invd = 11.0f / 30.0f;
        const float t0   = -15.0f - 3.0f * dist;
        float x = fminf(fmaxf(xi, -15.0f), 15.0f - 1e-6f);
        float u = (x - t0) * invd;
        int   i = (int)floorf(u);
        i = min(13, max(3, i));
        const float uu  = u - (float)i;
        const float om  = 1.0f - uu;
        const float uu2 = uu * uu, uu3 = uu2 * uu;
        const float sixth = 1.0f / 6.0f;
        f32x4 w = { om * om * om * sixth,
                    (3.0f * uu3 - 6.0f * uu2 + 4.0f) * sixth,
                    (-3.0f * uu3 + 3.0f * uu2 + 3.0f * uu + 1.0f) * sixth,
                    uu3 * sixth };
        wgt4[r][c] = w;
        ibk[r][c]  = (unsigned char)(i - 3);
    }

    // ---- Per-thread pair decode (p1 = tid, p2 = tid+256) ----
    const int p1 = tid;
    int v1 = (int)((1.0f + sqrtf(8.0f * (float)p1 + 1.0f)) * 0.5f);
    while (v1 * (v1 - 1) / 2 > p1) --v1;
    while ((v1 + 1) * v1 / 2 <= p1) ++v1;
    const int c1 = p1 - v1 * (v1 - 1) / 2;
    const int o1 = seg_of(v1) + c1;

    const int  p2   = tid + 256;
    const bool has2 = (p2 < NPAIR);
    int c2 = 0, o2 = 0;
    if (has2) {
        int v2 = (int)((1.0f + sqrtf(8.0f * (float)p2 + 1.0f)) * 0.5f);
        while (v2 * (v2 - 1) / 2 > p2) --v2;
        while ((v2 + 1) * v2 / 2 <= p2) ++v2;
        c2 = p2 - v2 * (v2 - 1) / 2;
        o2 = seg_of(v2) + c2;
    }
    __syncthreads();

    // ---- Phase A: lam for all 496 pairs x 8 rows ----
    #pragma unroll
    for (int r = 0; r < ROWS; ++r) {
        {
            const int   i = ibk[r][c1];
            const f32x4 w = wgt4[r][c1];
            const f32x4 q = ptv[i * NPAIR + p1];     // lanes contiguous in p
            lam[r][o1] = w.x * q.x + w.y * q.y + w.z * q.z + w.w * q.w;
        }
        if (has2) {
            const int   i = ibk[r][c2];
            const f32x4 w = wgt4[r][c2];
            const f32x4 q = ptv[i * NPAIR + p2];
            lam[r][o2] = w.x * q.x + w.y * q.y + w.z * q.z + w.w * q.w;
        }
    }
    __syncthreads();

    // ---- Phase B: emit lm (coalesced float4 stores) + out ----
    const int v    = tid >> 3;
    const int c0   = (tid & 7) << 2;
    const int segv = seg_of(v);
    float* lmp = lm + (size_t)n0 * (VDIM * VDIM) + tid * 4;

    #pragma unroll
    for (int r = 0; r < ROWS; ++r, lmp += VDIM * VDIM) {
        const int n = n0 + r;
        if (n >= N) break;
        const f32x4 lq = *(const f32x4*)&lam[r][segv + c0];
        const f32x4 xq = *(const f32x4*)&xin[r][c0];
        float vals[4];
        float partial = 0.0f;
        #pragma unroll
        for (int j = 0; j < 4; ++j) {
            const int c = c0 + j;
            const float lv = (j == 0) ? lq.x : (j == 1) ? lq.y : (j == 2) ? lq.z : lq.w;
            const float xv = (j == 0) ? xq.x : (j == 1) ? xq.y : (j == 2) ? xq.z : xq.w;
            const float val = (c < v) ? lv : ((c == v) ? 1.0f : 0.0f);
            vals[j] = val;
            partial += val * xv;
        }
        f32x4 f4 = { vals[0], vals[1], vals[2], vals[3] };
        *(f32x4*)lmp = f4;

        partial += __shfl_down(partial, 4, 8);
        partial += __shfl_down(partial, 2, 8);
        partial += __shfl_down(partial, 1, 8);
        if ((tid & 7) == 0) out[n * VDIM + v] = partial;
    }
}

extern "C" void kernel_launch(void* const* d_in, const int* in_sizes, int n_in,
                              void* d_out, int out_size, void* d_ws, size_t ws_size,
                              hipStream_t stream) {
    const float* input  = (const float*)d_in[0];   // [N,32]
    // d_in[1] = log_d : unused by the reference
    const float* params = (const float*)d_in[2];   // [14,496]
    const int N = in_sizes[0] / VDIM;              // 16384

    float* out  = (float*)d_out;                   // [N,32]
    float* lm   = out + (size_t)N * VDIM;          // [N,32,32]
    float* pens = lm + (size_t)N * VDIM * VDIM;    // [3]

    f32x4* ptv = (f32x4*)d_ws;                     // [11][496] float4 = 87 KB

    Decorrelation_prep<<<NINT, 256, 0, stream>>>(params, ptv, pens);

    const int nb = (N + ROWS - 1) / ROWS;          // 2048
    Decorrelation_35270271435435_kernel<<<nb, 256, 0, stream>>>(
        input, ptv, out, lm, N);
}